// Round 8
// baseline (649.773 us; speedup 1.0000x reference)
//
#include <hip/hip_runtime.h>
#include <hip/hip_bf16.h>
#include <hip/hip_fp16.h>
#include <stdint.h>

// Problem constants (QLoRALinear_34454227649197)
#define M_DIM 16384   // TOK
#define N_DIM 4096    // OUT
#define K_DIM 4096    // IN
#define NGROUP 64     // K_DIM / 64
#define NT    64      // K-tiles (K_DIM / 64)

// Harness dtype note (round-3 forensics): float16 arrays are presented as
// FLOAT32 on device. x = const float*, out = float*.

typedef _Float16 f16x8 __attribute__((ext_vector_type(8)));
typedef _Float16 f16x2 __attribute__((ext_vector_type(2)));
typedef float f32x4 __attribute__((ext_vector_type(4)));

typedef __attribute__((address_space(3))) uint32_t lds_u32_t;
typedef const __attribute__((address_space(1))) uint32_t glob_u32_t;

__device__ __forceinline__ void gload16(const void* g, void* l) {
    // global_load_lds_dwordx4: LDS dest = wave-uniform base + lane*16;
    // global source per-lane (pre-swizzled). Zero conflicts, rounds 5-7.
    __builtin_amdgcn_global_load_lds((glob_u32_t*)g, (lds_u32_t*)l, 16, 0, 0);
}

// ---------------------------------------------------------------------------
// Kernel 0: Xh[i] = (fp16) x[i]   (exact: x values are fp16-quantized)
// ---------------------------------------------------------------------------
__global__ __launch_bounds__(256) void convert_x_kernel(
    const float* __restrict__ x, _Float16* __restrict__ Xh)
{
    const size_t i = ((size_t)blockIdx.x * 256 + threadIdx.x) * 8;
    const float4 a = *reinterpret_cast<const float4*>(&x[i]);
    const float4 b = *reinterpret_cast<const float4*>(&x[i + 4]);
    f16x8 o;
    o[0] = (_Float16)a.x; o[1] = (_Float16)a.y;
    o[2] = (_Float16)a.z; o[3] = (_Float16)a.w;
    o[4] = (_Float16)b.x; o[5] = (_Float16)b.y;
    o[6] = (_Float16)b.z; o[7] = (_Float16)b.w;
    *reinterpret_cast<f16x8*>(&Xh[i]) = o;
}

// ---------------------------------------------------------------------------
// Kernel 1: W[local n][k] = (q[n0+n][k]-8)*scales[n0+n][k/64]
//                           + sum_r lB[n0+n][r]*lA[r][k]     (fp16 out)
// ---------------------------------------------------------------------------
__global__ __launch_bounds__(256) void dequant_lora_kernel(
    const int* __restrict__ q, const float* __restrict__ sc,
    const float* __restrict__ lA, const float* __restrict__ lB,
    _Float16* __restrict__ W, int n0)
{
    const int t   = threadIdx.x;
    const int o0l = blockIdx.x * 4;        // local chunk row base
    const int o0g = n0 + o0l;              // global OUT row base

    __shared__ float sScale[4][64];
    __shared__ float sB[4][16];
    sScale[t >> 6][t & 63] = sc[(size_t)(o0g + (t >> 6)) * NGROUP + (t & 63)];
    if (t < 64) sB[t >> 4][t & 15] = lB[(size_t)(o0g + (t >> 4)) * 16 + (t & 15)];
    __syncthreads();

    for (int j = 0; j < 8; ++j) {
        const int i = j * 512 + t * 2;      // even; covers [0,4096)
        float l0[4] = {0.f, 0.f, 0.f, 0.f};
        float l1[4] = {0.f, 0.f, 0.f, 0.f};
        #pragma unroll
        for (int r = 0; r < 16; ++r) {
            const float2 a = *reinterpret_cast<const float2*>(&lA[(size_t)r * K_DIM + i]);
            #pragma unroll
            for (int row = 0; row < 4; ++row) {
                l0[row] = fmaf(sB[row][r], a.x, l0[row]);
                l1[row] = fmaf(sB[row][r], a.y, l1[row]);
            }
        }
        const int g = i >> 6;               // i even => i, i+1 same group
        #pragma unroll
        for (int row = 0; row < 4; ++row) {
            const int2 qv = *reinterpret_cast<const int2*>(&q[(size_t)(o0g + row) * K_DIM + i]);
            const float s = sScale[row][g];
            f16x2 h2;
            h2[0] = (_Float16)fmaf((float)(qv.x - 8), s, l0[row]);
            h2[1] = (_Float16)fmaf((float)(qv.y - 8), s, l1[row]);
            *reinterpret_cast<f16x2*>(&W[(size_t)(o0l + row) * K_DIM + i]) = h2;
        }
    }
}

// ---------------------------------------------------------------------------
// Kernel 2: out = Xh @ W^T — 256x256, BK=64, 8 waves (2M x 4N, 128x64/wave).
// Register-double-buffered fragments: phase p issues ds_reads for phase p+1's
// quadrant, then runs 16 MFMA on the previous reads -> LDS-read time hides
// under the matrix pipe (round-7 counters showed read+MFMA SERIALIZED:
// tile time = 2483+2313 cyc = sum, not max). 2 LDS dbuf, stage kt+1 at tile
// top; syncthreads at p2.5 (publishes next buf; vmcnt covered by ~3 phases)
// and tile end. Zero-conflict XOR swizzle throughout.
// ---------------------------------------------------------------------------
#define ABUF 32768                    // A: 256 rows x 128 B
#define BUF_BYTES 65536               // A (32K) + B (32K)

#define LDA(dst, AcP, mq, ks) do {                                          \
    const int swz_ = ((((ks) * 4 + hi) * 16) ^ swzB);                       \
    for (int i_ = 0; i_ < 4; ++i_)                                          \
        dst[i_] = *(const f16x8*)((AcP) +                                   \
            (wr * 128 + (mq) * 64 + i_ * 16 + r16) * 128 + swz_);           \
} while (0)

#define LDB(dst, BcP, ks) do {                                              \
    const int swz_ = ((((ks) * 4 + hi) * 16) ^ swzB);                       \
    for (int i_ = 0; i_ < 4; ++i_)                                          \
        dst[i_] = *(const f16x8*)((BcP) +                                   \
            (wc * 64 + i_ * 16 + r16) * 128 + swz_);                        \
} while (0)

#define MFMA16(aF, bF, mq) do {                                             \
    __builtin_amdgcn_s_setprio(1);                                          \
    for (int mi_ = 0; mi_ < 4; ++mi_)                                       \
        for (int ni_ = 0; ni_ < 4; ++ni_)                                   \
            acc[(mq) * 4 + mi_][ni_] = __builtin_amdgcn_mfma_f32_16x16x32_f16( \
                aF[mi_], bF[ni_], acc[(mq) * 4 + mi_][ni_], 0, 0, 0);       \
    __builtin_amdgcn_s_setprio(0);                                          \
    __builtin_amdgcn_sched_barrier(0);                                      \
} while (0)

#define STAGE(kt1) do {                                                     \
    char* d_ = ldsBase + (((kt1) & 1) * BUF_BYTES) + dOff;                  \
    const int kp_ = (kt1) * 64;                                             \
    for (int n_ = 0; n_ < 4; ++n_) {                                        \
        gload16(aSrc + (size_t)(n_ * 64) * K_DIM + kp_, d_ + n_ * 8192);    \
        gload16(bSrc + (size_t)(n_ * 64) * K_DIM + kp_, d_ + ABUF + n_ * 8192); \
    }                                                                       \
} while (0)

#define FENCE() __builtin_amdgcn_sched_barrier(0)

__global__ __launch_bounds__(512, 2) void gemm_bt_kernel(
    const _Float16* __restrict__ A,   // Xh chunk, [rows][K]
    const _Float16* __restrict__ B,   // W chunk,  [cols][K]
    float* __restrict__ C,
    int m0, int n0, int nbm, int nbn)
{
    alignas(16) __shared__ _Float16 lds[2 * 32768];   // 128 KiB

    const int t  = threadIdx.x;
    const int l  = t & 63;
    const int w  = t >> 6;          // 0..7
    const int wr = w >> 2;          // 0..1  (M: 128 rows)
    const int wc = w & 3;           // 0..3  (N: 64 cols)

    // m204 bijective XCD swizzle, then tail-safe GROUP_M=8.
    const int nwg  = nbm * nbn;
    const int orig = blockIdx.x;
    const int xcd  = orig & 7;
    const int qq = nwg >> 3, rr = nwg & 7;
    const int wg = (xcd < rr ? xcd * (qq + 1) : rr * (qq + 1) + (xcd - rr) * qq)
                 + (orig >> 3);
    const int gs    = 8 * nbn;
    const int group = wg / gs;
    const int start = group * 8;
    const int gsz   = (nbm - start < 8) ? (nbm - start) : 8;
    const int idg   = wg - group * gs;
    const int bm    = start + idg % gsz;
    const int bn    = idg / gsz;

    const int Mb = bm * 256;
    const int Nb = bn * 256;

    // Staging: 512 thr x 16B = 8 KB = 64 rows x 128 B per issue.
    const int rloc = t >> 3;                   // 0..63
    const int kswz = ((t & 7) ^ (rloc & 7)) * 8;
    const _Float16* aSrc = A + (size_t)(Mb + rloc) * K_DIM + kswz;
    const _Float16* bSrc = B + (size_t)(Nb + rloc) * K_DIM + kswz;
    char* const ldsBase = (char*)lds;
    const int dOff = t * 16;

    const int r16 = l & 15;
    const int hi  = l >> 4;           // 0..3
    const int swzB = (r16 & 7) * 16;  // row-dependent XOR part (bytes)

    f32x4 acc[8][4] = {};
    f16x8 aFX[4], aFY[4], bFX[4], bFY[4];

    // --- prologue: stage tile 0; preload p0 fragments of tile 0 ---
    STAGE(0);
    __syncthreads();
    {
        const char* Ac = ldsBase;
        const char* Bc = Ac + ABUF;
        LDB(bFX, Bc, 0);
        LDA(aFX, Ac, 0, 0);
        FENCE();
    }

    for (int kt = 0; kt < NT; ++kt) {
        const char* Ac  = ldsBase + (kt & 1) * BUF_BYTES;
        const char* Bc  = Ac + ABUF;
        const char* nAc = ldsBase + ((kt + 1) & 1) * BUF_BYTES;
        const char* nBc = nAc + ABUF;
        const bool more = (kt + 1) < NT;

        // Stage next tile into the other buffer (its old content fully read:
        // last reads completed before the end-of-tile barrier of kt-1).
        if (more) STAGE(kt + 1);
        FENCE();

        // p0: compute (ks0,mq0) on X; issue aFY <- (mq1,ks0)
        LDA(aFY, Ac, 1, 0);
        FENCE();
        MFMA16(aFX, bFX, 0);

        // p1: compute (ks0,mq1) on (aFY,bFX); issue bFY <- ks1, aFX <- (mq0,ks1)
        LDB(bFY, Bc, 1);
        LDA(aFX, Ac, 0, 1);
        FENCE();
        MFMA16(aFY, bFX, 1);

        // p2: compute (ks1,mq0) on (aFX,bFY); issue aFY <- (mq1,ks1)
        LDA(aFY, Ac, 1, 1);
        FENCE();
        MFMA16(aFX, bFY, 0);

        // p2.5: publish next tile (per-wave vmcnt(0) covered by ~3 phases of
        // compute; barrier makes every wave's staged rows visible).
        __syncthreads();

        // p3: compute (ks1,mq1) on (aFY,bFY); issue NEXT tile's p0 frags.
        if (more) {
            LDB(bFX, nBc, 0);
            LDA(aFX, nAc, 0, 0);
        }
        FENCE();
        MFMA16(aFY, bFY, 1);

        // end of tile: all reads of buf[kt&1] complete; bounds wave drift
        // before buf[kt&1] is restaged at the top of tile kt+1.
        __syncthreads();
    }

    // Epilogue: C/D layout col = lane&15, row = (lane>>4)*4 + reg. f32 stores.
    #pragma unroll
    for (int mi = 0; mi < 8; ++mi) {
        const int row0 = m0 + Mb + wr * 128 + mi * 16 + hi * 4;
        #pragma unroll
        for (int ni = 0; ni < 4; ++ni) {
            const int col = n0 + Nb + wc * 64 + ni * 16 + r16;
            const f32x4 v = acc[mi][ni];
            #pragma unroll
            for (int u = 0; u < 4; ++u)
                C[(size_t)(row0 + u) * N_DIM + col] = v[u];
        }
    }
}

extern "C" void kernel_launch(void* const* d_in, const int* in_sizes, int n_in,
                              void* d_out, int out_size, void* d_ws, size_t ws_size,
                              hipStream_t stream) {
    const float* x  = (const float*)d_in[0];   // fp16 values promoted to f32
    const int*   q  = (const int*)d_in[1];
    const float* sc = (const float*)d_in[2];
    const float* lA = (const float*)d_in[3];
    const float* lB = (const float*)d_in[4];
    float* out = (float*)d_out;                 // f32 output buffer

    // Workspace layout: [W: colC x K fp16][Xh: rowC x K fp16], chunk-looped.
    const size_t wfull = (size_t)N_DIM * K_DIM * 2;   // 32 MiB
    int colC, rowC;
    if (ws_size >= wfull + (size_t)256 * K_DIM * 2) {
        colC = N_DIM;
        size_t rows = (ws_size - wfull) / ((size_t)K_DIM * 2);
        rowC = (int)((rows / 256) * 256);
        if (rowC > M_DIM) rowC = M_DIM;
    } else {
        size_t half = ws_size / 2;
        colC = (int)((half / ((size_t)K_DIM * 2) / 256) * 256);
        if (colC < 256) colC = 256;
        if (colC > N_DIM) colC = N_DIM;
        size_t rows = (ws_size - (size_t)colC * K_DIM * 2) / ((size_t)K_DIM * 2);
        rowC = (int)((rows / 256) * 256);
        if (rowC < 256) rowC = 256;
        if (rowC > M_DIM) rowC = M_DIM;
    }
    _Float16* W  = (_Float16*)d_ws;
    _Float16* Xh = (_Float16*)d_ws + (size_t)colC * K_DIM;

    for (int n0 = 0; n0 < N_DIM; n0 += colC) {
        int cols = N_DIM - n0; if (cols > colC) cols = colC;
        dequant_lora_kernel<<<cols / 4, 256, 0, stream>>>(q, sc, lA, lB, W, n0);
        for (int m0 = 0; m0 < M_DIM; m0 += rowC) {
            int rows = M_DIM - m0; if (rows > rowC) rows = rowC;
            convert_x_kernel<<<(int)(((size_t)rows * K_DIM) / (256 * 8)), 256, 0, stream>>>(
                x + (size_t)m0 * K_DIM, Xh);
            gemm_bt_kernel<<<(rows / 256) * (cols / 256), 512, 0, stream>>>(
                Xh, W, out, m0, n0, rows / 256, cols / 256);
        }
    }
}